// Round 11
// baseline (722.219 us; speedup 1.0000x reference)
//
#include <hip/hip_runtime.h>

#define NL 16384          // row length
#define NB 64             // rows = blocks
#define NT 512            // threads per block (8 waves)
#define NC (NL / NT)      // 32 elements per thread
#define NW (NT / 64)      // 8 waves
#define N_ITER 12
#define N_IMFS 6

#pragma clang fp contract(off)   // everything unfused EXCEPT the explicit fmaf

#define HSZ (NL + (NL >> 5))   // +1 float per 32: lane bank = (33t+j)%32 -> 2-way max (free)
__device__ __forceinline__ int physi(int i) { return i + (i >> 5); }

#define FMAXV 3.402823466e38f

// Frozen bit-exact semantics (certified R9, absmax 0.0):
//  strict peaks on f32 h; frac = (float)(i-l)/(float)max(den,1);
//  env = fmaf(frac, r-l, l); overrides l<0 -> vr, n>=NL -> vl, tot<2 -> cummax/min;
//  mean = 0.5f*(envU+envL); h -= mean; freeze-h on converged iteration.
// R10 lesson: NO big per-thread arrays (spill cliff at capped VGPR). One array: nreg[32].
__global__ __launch_bounds__(NT, 2) void emd_main(
    const float* __restrict__ x, float* __restrict__ out,
    unsigned* cnt, double* sdsl, double* flsl) {
  __shared__ float h[HSZ];                       // 67584 B
  __shared__ int wLU[NW], wLL[NW], wNU[NW], wNL[NW];
  __shared__ float wMx[NW], wMn[NW];
  __shared__ unsigned wCT[NW];
  __shared__ int eLU[NW], eLL[NW], eNU[NW], eNL[NW];
  __shared__ float eMx[NW], eMn[NW];
  __shared__ unsigned sTot;
  __shared__ double tA[NW], tB[NW], tC[NW], tD[NW];
  __shared__ int sFlag;

  const int t = threadIdx.x;
  const int lane = t & 63;
  const int wv = t >> 6;
  const int row = blockIdx.x;
  const int base = t * NC;
  const float* xr = x + (size_t)row * NL;
  float* res = out + (size_t)N_IMFS * NB * NL + (size_t)row * NL;

  // init: h = x row (LDS, swizzled); res slab of d_out = x
  for (int m = 0; m < NC; m++) {
    int i = m * NT + t;
    float v = xr[i];
    h[physi(i)] = v;
    res[i] = v;
  }
  __syncthreads();

  unsigned ep = 0;
  bool done = false;

  for (int k = 0; k < N_IMFS; k++) {
    float* outk = out + (size_t)k * NB * NL + (size_t)row * NL;
    if (done) {  // globally-uniform skip (no barriers)
      for (int m = 0; m < NC; m++) outk[m * NT + t] = 0.0f;
      continue;
    }

    // ---------------- sifting ----------------
    for (int it = 0; it < N_ITER; it++) {
      // pass A: rolling walk -> peak masks, chunk summaries (f32 compares as R9)
      unsigned mU = 0, mL = 0;
      int lmU = -1, lmL = -1, cU = 0, cL = 0;
      float rmx = -FMAXV, rmn = FMAXV;
      {
        float hm = (base > 0) ? h[physi(base - 1)] : 0.0f;
        float hc = h[physi(base)];
        #pragma unroll
        for (int j = 0; j < NC; j++) {
          int i = base + j;
          float hp = (i + 1 < NL) ? h[physi(i + 1)] : 0.0f;
          bool in = (i > 0) && (i + 1 < NL);
          if (in && hm < hc && hc > hp) { mU |= (1u << j); lmU = i; cU++; }
          if (in && hm > hc && hc < hp) { mL |= (1u << j); lmL = i; cL++; }
          rmx = fmaxf(rmx, hc);
          rmn = fminf(rmn, hc);
          hm = hc; hc = hp;
        }
      }
      // per-element next-peak within chunk (packed; the ONE per-thread array)
      unsigned nreg[NC];
      {
        int nU = NL, nL2 = NL;
        #pragma unroll
        for (int j = NC - 1; j >= 0; j--) {
          if ((mU >> j) & 1) nU = base + j;
          if ((mL >> j) & 1) nL2 = base + j;
          nreg[j] = ((unsigned)nU << 16) | (unsigned)nL2;
        }
      }
      // wave-level scans (shuffles, no barriers)
      int iLU = lmU, iLL = lmL;
      float iMx = rmx, iMn = rmn;
      int iNU = (int)(nreg[0] >> 16), iNL = (int)(nreg[0] & 0xffffu);
      unsigned ict = ((unsigned)cU << 16) | (unsigned)cL;
      #pragma unroll
      for (int o = 1; o < 64; o <<= 1) {
        int a = __shfl_up(iLU, o, 64);
        int b = __shfl_up(iLL, o, 64);
        float fa = __shfl_up(iMx, o, 64);
        float fb = __shfl_up(iMn, o, 64);
        int c = __shfl_down(iNU, o, 64);
        int d = __shfl_down(iNL, o, 64);
        unsigned cc = __shfl_down(ict, o, 64);
        if (lane >= o) { iLU = max(iLU, a); iLL = max(iLL, b);
                         iMx = fmaxf(iMx, fa); iMn = fminf(iMn, fb); }
        if (lane + o < 64) { iNU = min(iNU, c); iNL = min(iNL, d); ict += cc; }
      }
      if (lane == 63) { wLU[wv] = iLU; wLL[wv] = iLL; wMx[wv] = iMx; wMn[wv] = iMn; }
      if (lane == 0)  { wNU[wv] = iNU; wNL[wv] = iNL; wCT[wv] = ict; }
      __syncthreads();
      if (t == 0) {  // 8-entry serial combine -> exclusive wave carries
        int aLU = -1, aLL = -1; float aMx = -FMAXV, aMn = FMAXV; unsigned tot = 0;
        for (int w = 0; w < NW; w++) {
          eLU[w] = aLU; aLU = max(aLU, wLU[w]);
          eLL[w] = aLL; aLL = max(aLL, wLL[w]);
          eMx[w] = aMx; aMx = fmaxf(aMx, wMx[w]);
          eMn[w] = aMn; aMn = fminf(aMn, wMn[w]);
          tot += wCT[w];
        }
        int aNU = NL, aNL = NL;
        for (int w = NW - 1; w >= 0; w--) {
          eNU[w] = aNU; aNU = min(aNU, wNU[w]);
          eNL[w] = aNL; aNL = min(aNL, wNL[w]);
        }
        sTot = tot;
      }
      __syncthreads();
      unsigned tot = sTot;
      int totU = (int)(tot >> 16), totL = (int)(tot & 0xffffu);
      int pLU = __shfl_up(iLU, 1, 64); if (lane == 0) pLU = -1;
      int pLL = __shfl_up(iLL, 1, 64); if (lane == 0) pLL = -1;
      float pMx = __shfl_up(iMx, 1, 64); if (lane == 0) pMx = -FMAXV;
      float pMn = __shfl_up(iMn, 1, 64); if (lane == 0) pMn = FMAXV;
      int sNUl = __shfl_down(iNU, 1, 64); if (lane == 63) sNUl = NL;
      int sNLl = __shfl_down(iNL, 1, 64); if (lane == 63) sNLl = NL;
      int clU = max(eLU[wv], pLU), clL = max(eLL[wv], pLL);
      float crx = fmaxf(eMx[wv], pMx), crn = fminf(eMn[wv], pMn);
      int cnU = min(eNU[wv], sNUl), cnL = min(eNL[wv], sNLl);

      // pass C: envelopes + mean (frozen f32 ladder), endpoint gather caching
      double pm2 = 0.0, ph2 = 0.0;
      {
        int lU = clU, lL = clL;
        float rx = crx, rn = crn;
        int gA = -0x7fffffff, gB = -0x7fffffff, gC = -0x7fffffff, gD = -0x7fffffff;
        float vl = 0.0f, vr = 0.0f, wl = 0.0f, wr = 0.0f;
        #pragma unroll
        for (int j = 0; j < NC; j++) {
          int i = base + j;
          float hc = h[physi(i)];
          if ((mU >> j) & 1) lU = i;
          if ((mL >> j) & 1) lL = i;
          rx = fmaxf(rx, hc);
          rn = fminf(rn, hc);
          int nUv = (int)(nreg[j] >> 16);     if (cnU < nUv) nUv = cnU;
          int nLv = (int)(nreg[j] & 0xffffu); if (cnL < nLv) nLv = cnL;
          if (lU != gA)  { gA = lU;  vl = h[physi(lU < 0 ? 0 : lU)]; }
          if (nUv != gB) { gB = nUv; vr = h[physi(nUv >= NL ? NL - 1 : nUv)]; }
          if (lL != gC)  { gC = lL;  wl = h[physi(lL < 0 ? 0 : lL)]; }
          if (nLv != gD) { gD = nLv; wr = h[physi(nLv >= NL ? NL - 1 : nLv)]; }
          int den = nUv - lU;
          float fracU = (float)(i - lU) / (float)(den > 0 ? den : 1);
          float envU = (den > 0) ? __builtin_fmaf(fracU, vr - vl, vl) : vl;
          if (lU < 0) envU = vr;
          if (nUv >= NL) envU = vl;
          if (totU < 2) envU = rx;
          int den2 = nLv - lL;
          float fracL = (float)(i - lL) / (float)(den2 > 0 ? den2 : 1);
          float envL = (den2 > 0) ? __builtin_fmaf(fracL, wr - wl, wl) : wl;
          if (lL < 0) envL = wr;
          if (nLv >= NL) envL = wl;
          if (totL < 2) envL = rn;
          float mn = 0.5f * (envU + envL);
          nreg[j] = __float_as_uint(mn);   // slot consumed; reuse for mean bits
          pm2 += (double)mn * (double)mn;
          ph2 += (double)hc * (double)hc;
        }
      }
      // fused block reduction of (pm2, ph2): wave shuffle, publish, t0 combines
      #pragma unroll
      for (int o = 1; o < 64; o <<= 1) {
        double a = __shfl_down(pm2, o, 64);
        double b = __shfl_down(ph2, o, 64);
        if (lane + o < 64) { pm2 += a; ph2 += b; }
      }
      if (lane == 0) { tA[wv] = pm2; tB[wv] = ph2; }
      // ---- grid barrier + convergence decision ----
      ep++;
      __syncthreads();   // orders tA/tB writes before t0 reads
      if (t == 0) {
        double sA = 0.0, sB = 0.0;
        for (int w = 0; w < NW; w++) { sA += tA[w]; sB += tB[w]; }
        atomicAdd(&sdsl[(k * N_ITER + it) * 2 + 0], sA);
        atomicAdd(&sdsl[(k * N_ITER + it) * 2 + 1], sB);
        __hip_atomic_fetch_add(cnt, 1u, __ATOMIC_ACQ_REL, __HIP_MEMORY_SCOPE_AGENT);
        unsigned tgt = ep * gridDim.x;
        while (__hip_atomic_load(cnt, __ATOMIC_ACQUIRE, __HIP_MEMORY_SCOPE_AGENT) < tgt)
          __builtin_amdgcn_s_sleep(1);
        double m2 = __hip_atomic_load(&sdsl[(k * N_ITER + it) * 2 + 0],
                                      __ATOMIC_RELAXED, __HIP_MEMORY_SCOPE_AGENT);
        double h2 = __hip_atomic_load(&sdsl[(k * N_ITER + it) * 2 + 1],
                                      __ATOMIC_RELAXED, __HIP_MEMORY_SCOPE_AGENT);
        sFlag = (m2 / (h2 + 1e-8) < 0.05) ? 1 : 0;
      }
      __syncthreads();
      if (sFlag) break;   // converged: h frozen (JAX done-latch semantics)
      #pragma unroll
      for (int j = 0; j < NC; j++)
        h[physi(base + j)] -= __uint_as_float(nreg[j]);
      __syncthreads();
    }

    // ------------- flatness test + outputs (f32 values, f64 sums) -------------
    double s1 = 0.0, s2 = 0.0, s3 = 0.0, s4 = 0.0;
    {
      float rc = res[base] - h[physi(base)];
      #pragma unroll
      for (int j = 0; j < NC; j++) {
        int i = base + j;
        s1 += (double)rc;
        s2 += (double)rc * (double)rc;
        if (i + 1 < NL) {
          float rnx = res[i + 1] - h[physi(i + 1)];
          float d = rnx - rc;
          s3 += (double)d;
          s4 += (double)d * (double)d;
          rc = rnx;
        }
      }
    }
    #pragma unroll
    for (int o = 1; o < 64; o <<= 1) {
      double a = __shfl_down(s1, o, 64);
      double b = __shfl_down(s2, o, 64);
      double c = __shfl_down(s3, o, 64);
      double d = __shfl_down(s4, o, 64);
      if (lane + o < 64) { s1 += a; s2 += b; s3 += c; s4 += d; }
    }
    if (lane == 0) { tA[wv] = s1; tB[wv] = s2; tC[wv] = s3; tD[wv] = s4; }
    __syncthreads();   // orders publishes AND all cross-thread h/res reads above
    if (t == 0) {
      double S1 = 0.0, S2 = 0.0, S3 = 0.0, S4 = 0.0;
      for (int w = 0; w < NW; w++) { S1 += tA[w]; S2 += tB[w]; S3 += tC[w]; S4 += tD[w]; }
      atomicAdd(&flsl[k * 4 + 0], S1);
      atomicAdd(&flsl[k * 4 + 1], S2);
      atomicAdd(&flsl[k * 4 + 2], S3);
      atomicAdd(&flsl[k * 4 + 3], S4);
    }
    // outputs: IMF k = h; res -= h; h <- new res  (float4 on global, scalar on LDS)
    #pragma unroll
    for (int q = 0; q < NC / 4; q++) {
      int i0 = base + q * 4;
      float4 rv = *(const float4*)&res[i0];
      float4 hv;
      hv.x = h[physi(i0 + 0)]; hv.y = h[physi(i0 + 1)];
      hv.z = h[physi(i0 + 2)]; hv.w = h[physi(i0 + 3)];
      float4 rq = make_float4(rv.x - hv.x, rv.y - hv.y, rv.z - hv.z, rv.w - hv.w);
      *(float4*)&outk[i0] = hv;
      *(float4*)&res[i0] = rq;
      h[physi(i0 + 0)] = rq.x; h[physi(i0 + 1)] = rq.y;
      h[physi(i0 + 2)] = rq.z; h[physi(i0 + 3)] = rq.w;
    }
    // ---- grid barrier + flatness decision ----
    ep++;
    __syncthreads();
    if (t == 0) {
      __hip_atomic_fetch_add(cnt, 1u, __ATOMIC_ACQ_REL, __HIP_MEMORY_SCOPE_AGENT);
      unsigned tgt = ep * gridDim.x;
      while (__hip_atomic_load(cnt, __ATOMIC_ACQUIRE, __HIP_MEMORY_SCOPE_AGENT) < tgt)
        __builtin_amdgcn_s_sleep(1);
      double S1 = __hip_atomic_load(&flsl[k * 4 + 0], __ATOMIC_RELAXED, __HIP_MEMORY_SCOPE_AGENT);
      double S2 = __hip_atomic_load(&flsl[k * 4 + 1], __ATOMIC_RELAXED, __HIP_MEMORY_SCOPE_AGENT);
      double S3 = __hip_atomic_load(&flsl[k * 4 + 2], __ATOMIC_RELAXED, __HIP_MEMORY_SCOPE_AGENT);
      double S4 = __hip_atomic_load(&flsl[k * 4 + 3], __ATOMIC_RELAXED, __HIP_MEMORY_SCOPE_AGENT);
      double nr = (double)NB * (double)NL;
      double nd = (double)NB * (double)(NL - 1);
      double varr = (S2 - S1 * S1 / nr) / (nr - 1.0);
      double vard = (S4 - S3 * S3 / nd) / (nd - 1.0);
      sFlag = (vard < 0.05 * varr) ? 1 : 0;
    }
    __syncthreads();
    done = done || (sFlag != 0);
  }
}

extern "C" void kernel_launch(void* const* d_in, const int* in_sizes, int n_in,
                              void* d_out, int out_size, void* d_ws, size_t ws_size,
                              hipStream_t stream) {
  const float* x = (const float*)d_in[0];
  float* out = (float*)d_out;
  // ws layout: [0] barrier counter; [256] sd slots (6*12*2 dbl); [1408] flat slots (6*4 dbl)
  size_t zb = ws_size < 4096 ? ws_size : 4096;
  hipMemsetAsync(d_ws, 0, zb, stream);
  unsigned* cnt = (unsigned*)d_ws;
  double* sdsl = (double*)((char*)d_ws + 256);
  double* flsl = (double*)((char*)d_ws + 256 + (size_t)N_IMFS * N_ITER * 2 * 8);
  hipLaunchKernelGGL(emd_main, dim3(NB), dim3(NT), 0, stream, x, out, cnt, sdsl, flsl);
}

// Round 12
// 330.259 us; speedup vs baseline: 2.1868x; 2.1868x over previous
//
#include <hip/hip_runtime.h>

#define NL 16384          // row length
#define NB 64             // rows = blocks
#define NT 512            // threads per block (8 waves)
#define NC (NL / NT)      // 32 elements per thread == bits in the peak mask
#define NW (NT / 64)      // 8 waves
#define N_ITER 12
#define N_IMFS 6

#pragma clang fp contract(off)   // everything unfused EXCEPT the explicit fmaf

#define HSZ (NL + (NL >> 5))   // +1 float per 32: 2-way-max banking (free)
__device__ __forceinline__ int physi(int i) { return i + (i >> 5); }

#define FMAXV 3.402823466e38f

// Frozen bit-exact semantics (certified R9/R11, absmax 0.0).
// R10/R11 lesson: per-thread arrays spill to scratch at this occupancy ->
// ~150MB/dispatch of scratch traffic. This version is ARRAY-FREE: the chunk
// peak masks are single u32s; per-element prev/next peak come from ffs/clz;
// the mean lives in a second LDS buffer.
__global__ __launch_bounds__(NT, 2) void emd_main(
    const float* __restrict__ x, float* __restrict__ out,
    unsigned* cnt, double* sdsl, double* flsl) {
  __shared__ float h[HSZ];        // 67584 B
  __shared__ float meanb[HSZ];    // 67584 B
  __shared__ int wLU[NW], wLL[NW], wNU[NW], wNL[NW];
  __shared__ float wMx[NW], wMn[NW];
  __shared__ unsigned wCT[NW];
  __shared__ int eLU[NW], eLL[NW], eNU[NW], eNL[NW];
  __shared__ float eMx[NW], eMn[NW];
  __shared__ unsigned sTot;
  __shared__ double tA[NW], tB[NW], tC[NW], tD[NW];
  __shared__ int sFlag;

  const int t = threadIdx.x;
  const int lane = t & 63;
  const int wv = t >> 6;
  const int row = blockIdx.x;
  const int base = t * NC;
  const float* xr = x + (size_t)row * NL;
  float* res = out + (size_t)N_IMFS * NB * NL + (size_t)row * NL;

  // init: h = x row (LDS, swizzled); res slab of d_out = x
  for (int m = 0; m < NC; m++) {
    int i = m * NT + t;
    float v = xr[i];
    h[physi(i)] = v;
    res[i] = v;
  }
  __syncthreads();

  unsigned ep = 0;
  bool done = false;

  for (int k = 0; k < N_IMFS; k++) {
    float* outk = out + (size_t)k * NB * NL + (size_t)row * NL;
    if (done) {  // globally-uniform skip (no barriers)
      for (int m = 0; m < NC; m++) outk[m * NT + t] = 0.0f;
      continue;
    }

    // ---------------- sifting ----------------
    for (int it = 0; it < N_ITER; it++) {
      // pass A: rolling walk -> peak masks + chunk summaries (f32 compares as R9)
      unsigned mU = 0, mL = 0;
      int lmU = -1, lmL = -1, cU = 0, cL = 0;
      float rmx = -FMAXV, rmn = FMAXV;
      {
        float hm = (base > 0) ? h[physi(base - 1)] : 0.0f;
        float hc = h[physi(base)];
        #pragma unroll
        for (int j = 0; j < NC; j++) {
          int i = base + j;
          float hp = (i + 1 < NL) ? h[physi(i + 1)] : 0.0f;
          bool in = (i > 0) && (i + 1 < NL);
          if (in && hm < hc && hc > hp) { mU |= (1u << j); lmU = i; cU++; }
          if (in && hm > hc && hc < hp) { mL |= (1u << j); lmL = i; cL++; }
          rmx = fmaxf(rmx, hc);
          rmn = fminf(rmn, hc);
          hm = hc; hc = hp;
        }
      }
      // wave-level scans (shuffles, no barriers)
      int iLU = lmU, iLL = lmL;
      float iMx = rmx, iMn = rmn;
      int iNU = mU ? (base + __ffs(mU) - 1) : NL;
      int iNL = mL ? (base + __ffs(mL) - 1) : NL;
      unsigned ict = ((unsigned)cU << 16) | (unsigned)cL;
      #pragma unroll
      for (int o = 1; o < 64; o <<= 1) {
        int a = __shfl_up(iLU, o, 64);
        int b = __shfl_up(iLL, o, 64);
        float fa = __shfl_up(iMx, o, 64);
        float fb = __shfl_up(iMn, o, 64);
        int c = __shfl_down(iNU, o, 64);
        int d = __shfl_down(iNL, o, 64);
        unsigned cc = __shfl_down(ict, o, 64);
        if (lane >= o) { iLU = max(iLU, a); iLL = max(iLL, b);
                         iMx = fmaxf(iMx, fa); iMn = fminf(iMn, fb); }
        if (lane + o < 64) { iNU = min(iNU, c); iNL = min(iNL, d); ict += cc; }
      }
      if (lane == 63) { wLU[wv] = iLU; wLL[wv] = iLL; wMx[wv] = iMx; wMn[wv] = iMn; }
      if (lane == 0)  { wNU[wv] = iNU; wNL[wv] = iNL; wCT[wv] = ict; }
      __syncthreads();
      if (t == 0) {  // 8-entry serial combine -> exclusive wave carries
        int aLU = -1, aLL = -1; float aMx = -FMAXV, aMn = FMAXV; unsigned tot = 0;
        for (int w = 0; w < NW; w++) {
          eLU[w] = aLU; aLU = max(aLU, wLU[w]);
          eLL[w] = aLL; aLL = max(aLL, wLL[w]);
          eMx[w] = aMx; aMx = fmaxf(aMx, wMx[w]);
          eMn[w] = aMn; aMn = fminf(aMn, wMn[w]);
          tot += wCT[w];
        }
        int aNU = NL, aNL = NL;
        for (int w = NW - 1; w >= 0; w--) {
          eNU[w] = aNU; aNU = min(aNU, wNU[w]);
          eNL[w] = aNL; aNL = min(aNL, wNL[w]);
        }
        sTot = tot;
      }
      __syncthreads();
      unsigned tot = sTot;
      int totU = (int)(tot >> 16), totL = (int)(tot & 0xffffu);
      int pLU = __shfl_up(iLU, 1, 64); if (lane == 0) pLU = -1;
      int pLL = __shfl_up(iLL, 1, 64); if (lane == 0) pLL = -1;
      float pMx = __shfl_up(iMx, 1, 64); if (lane == 0) pMx = -FMAXV;
      float pMn = __shfl_up(iMn, 1, 64); if (lane == 0) pMn = FMAXV;
      int sNUl = __shfl_down(iNU, 1, 64); if (lane == 63) sNUl = NL;
      int sNLl = __shfl_down(iNL, 1, 64); if (lane == 63) sNLl = NL;
      const int clU = max(eLU[wv], pLU), clL = max(eLL[wv], pLL);
      const float crx = fmaxf(eMx[wv], pMx), crn = fminf(eMn[wv], pMn);
      const int cnU = min(eNU[wv], sNUl), cnL = min(eNL[wv], sNLl);

      // pass C: envelopes + mean (frozen f32 ladder); prev/next peaks from
      // mask bit ops; endpoint gathers cached per peak segment; mean -> LDS
      double pm2 = 0.0, ph2 = 0.0;
      {
        float rx = crx, rn = crn;
        int gA = -0x7fffffff, gB = -0x7fffffff, gC = -0x7fffffff, gD = -0x7fffffff;
        float vl = 0.0f, vr = 0.0f, wl = 0.0f, wr = 0.0f;
        #pragma unroll
        for (int j = 0; j < NC; j++) {
          int i = base + j;
          float hc = h[physi(i)];
          rx = fmaxf(rx, hc);
          rn = fminf(rn, hc);
          unsigned lowm = 0xFFFFFFFFu >> (31 - j);   // bits <= j
          unsigned highm = 0xFFFFFFFFu << j;         // bits >= j
          unsigned a;
          a = mU & lowm;  int lU  = a ? (base + 31 - __clz(a)) : clU;
          a = mL & lowm;  int lL  = a ? (base + 31 - __clz(a)) : clL;
          a = mU & highm; int nUv = a ? (base + __ffs(a) - 1) : cnU;
          a = mL & highm; int nLv = a ? (base + __ffs(a) - 1) : cnL;
          if (lU != gA)  { gA = lU;  vl = h[physi(lU < 0 ? 0 : lU)]; }
          if (nUv != gB) { gB = nUv; vr = h[physi(nUv >= NL ? NL - 1 : nUv)]; }
          if (lL != gC)  { gC = lL;  wl = h[physi(lL < 0 ? 0 : lL)]; }
          if (nLv != gD) { gD = nLv; wr = h[physi(nLv >= NL ? NL - 1 : nLv)]; }
          int den = nUv - lU;
          float fracU = (float)(i - lU) / (float)(den > 0 ? den : 1);
          float envU = (den > 0) ? __builtin_fmaf(fracU, vr - vl, vl) : vl;
          if (lU < 0) envU = vr;
          if (nUv >= NL) envU = vl;
          if (totU < 2) envU = rx;
          int den2 = nLv - lL;
          float fracL = (float)(i - lL) / (float)(den2 > 0 ? den2 : 1);
          float envL = (den2 > 0) ? __builtin_fmaf(fracL, wr - wl, wl) : wl;
          if (lL < 0) envL = wr;
          if (nLv >= NL) envL = wl;
          if (totL < 2) envL = rn;
          float mn = 0.5f * (envU + envL);
          meanb[physi(i)] = mn;
          pm2 += (double)mn * (double)mn;
          ph2 += (double)hc * (double)hc;
        }
      }
      // fused block reduction of (pm2, ph2): wave shuffle, publish, t0 combines
      #pragma unroll
      for (int o = 1; o < 64; o <<= 1) {
        double a = __shfl_down(pm2, o, 64);
        double b = __shfl_down(ph2, o, 64);
        if (lane + o < 64) { pm2 += a; ph2 += b; }
      }
      if (lane == 0) { tA[wv] = pm2; tB[wv] = ph2; }
      // ---- grid barrier + convergence decision ----
      ep++;
      __syncthreads();   // orders tA/tB (and meanb) before t0 reads / reuse
      if (t == 0) {
        double sA = 0.0, sB = 0.0;
        for (int w = 0; w < NW; w++) { sA += tA[w]; sB += tB[w]; }
        atomicAdd(&sdsl[(k * N_ITER + it) * 2 + 0], sA);
        atomicAdd(&sdsl[(k * N_ITER + it) * 2 + 1], sB);
        __hip_atomic_fetch_add(cnt, 1u, __ATOMIC_ACQ_REL, __HIP_MEMORY_SCOPE_AGENT);
        unsigned tgt = ep * gridDim.x;
        while (__hip_atomic_load(cnt, __ATOMIC_ACQUIRE, __HIP_MEMORY_SCOPE_AGENT) < tgt)
          __builtin_amdgcn_s_sleep(1);
        double m2 = __hip_atomic_load(&sdsl[(k * N_ITER + it) * 2 + 0],
                                      __ATOMIC_RELAXED, __HIP_MEMORY_SCOPE_AGENT);
        double h2 = __hip_atomic_load(&sdsl[(k * N_ITER + it) * 2 + 1],
                                      __ATOMIC_RELAXED, __HIP_MEMORY_SCOPE_AGENT);
        sFlag = (m2 / (h2 + 1e-8) < 0.05) ? 1 : 0;
      }
      __syncthreads();
      if (sFlag) break;   // converged: h frozen (JAX done-latch semantics)
      // subtract: h -= mean (both swizzled identically -> float4 safe)
      #pragma unroll
      for (int q = 0; q < NC / 4; q++) {
        int p0 = physi(base + q * 4);
        float4 hv = *(const float4*)&h[p0];
        float4 mv = *(const float4*)&meanb[p0];
        hv.x -= mv.x; hv.y -= mv.y; hv.z -= mv.z; hv.w -= mv.w;
        *(float4*)&h[p0] = hv;
      }
      __syncthreads();
    }

    // ------------- flatness test + outputs (f32 values, f64 sums) -------------
    double s1 = 0.0, s2 = 0.0, s3 = 0.0, s4 = 0.0;
    {
      float rc = res[base] - h[physi(base)];
      #pragma unroll
      for (int j = 0; j < NC; j++) {
        int i = base + j;
        s1 += (double)rc;
        s2 += (double)rc * (double)rc;
        if (i + 1 < NL) {
          float rnx = res[i + 1] - h[physi(i + 1)];
          float d = rnx - rc;
          s3 += (double)d;
          s4 += (double)d * (double)d;
          rc = rnx;
        }
      }
    }
    #pragma unroll
    for (int o = 1; o < 64; o <<= 1) {
      double a = __shfl_down(s1, o, 64);
      double b = __shfl_down(s2, o, 64);
      double c = __shfl_down(s3, o, 64);
      double d = __shfl_down(s4, o, 64);
      if (lane + o < 64) { s1 += a; s2 += b; s3 += c; s4 += d; }
    }
    if (lane == 0) { tA[wv] = s1; tB[wv] = s2; tC[wv] = s3; tD[wv] = s4; }
    __syncthreads();   // orders publishes AND all cross-thread h/res reads above
    if (t == 0) {
      double S1 = 0.0, S2 = 0.0, S3 = 0.0, S4 = 0.0;
      for (int w = 0; w < NW; w++) { S1 += tA[w]; S2 += tB[w]; S3 += tC[w]; S4 += tD[w]; }
      atomicAdd(&flsl[k * 4 + 0], S1);
      atomicAdd(&flsl[k * 4 + 1], S2);
      atomicAdd(&flsl[k * 4 + 2], S3);
      atomicAdd(&flsl[k * 4 + 3], S4);
    }
    // outputs: IMF k = h; res -= h; h <- new res
    #pragma unroll
    for (int q = 0; q < NC / 4; q++) {
      int i0 = base + q * 4;
      int p0 = physi(i0);
      float4 rv = *(const float4*)&res[i0];
      float4 hv = *(const float4*)&h[p0];
      float4 rq = make_float4(rv.x - hv.x, rv.y - hv.y, rv.z - hv.z, rv.w - hv.w);
      *(float4*)&outk[i0] = hv;
      *(float4*)&res[i0] = rq;
      *(float4*)&h[p0] = rq;
    }
    // ---- grid barrier + flatness decision ----
    ep++;
    __syncthreads();
    if (t == 0) {
      __hip_atomic_fetch_add(cnt, 1u, __ATOMIC_ACQ_REL, __HIP_MEMORY_SCOPE_AGENT);
      unsigned tgt = ep * gridDim.x;
      while (__hip_atomic_load(cnt, __ATOMIC_ACQUIRE, __HIP_MEMORY_SCOPE_AGENT) < tgt)
        __builtin_amdgcn_s_sleep(1);
      double S1 = __hip_atomic_load(&flsl[k * 4 + 0], __ATOMIC_RELAXED, __HIP_MEMORY_SCOPE_AGENT);
      double S2 = __hip_atomic_load(&flsl[k * 4 + 1], __ATOMIC_RELAXED, __HIP_MEMORY_SCOPE_AGENT);
      double S3 = __hip_atomic_load(&flsl[k * 4 + 2], __ATOMIC_RELAXED, __HIP_MEMORY_SCOPE_AGENT);
      double S4 = __hip_atomic_load(&flsl[k * 4 + 3], __ATOMIC_RELAXED, __HIP_MEMORY_SCOPE_AGENT);
      double nr = (double)NB * (double)NL;
      double nd = (double)NB * (double)(NL - 1);
      double varr = (S2 - S1 * S1 / nr) / (nr - 1.0);
      double vard = (S4 - S3 * S3 / nd) / (nd - 1.0);
      sFlag = (vard < 0.05 * varr) ? 1 : 0;
    }
    __syncthreads();
    done = done || (sFlag != 0);
  }
}

extern "C" void kernel_launch(void* const* d_in, const int* in_sizes, int n_in,
                              void* d_out, int out_size, void* d_ws, size_t ws_size,
                              hipStream_t stream) {
  const float* x = (const float*)d_in[0];
  float* out = (float*)d_out;
  // ws layout: [0] barrier counter; [256] sd slots (6*12*2 dbl); [1408] flat slots (6*4 dbl)
  size_t zb = ws_size < 4096 ? ws_size : 4096;
  hipMemsetAsync(d_ws, 0, zb, stream);
  unsigned* cnt = (unsigned*)d_ws;
  double* sdsl = (double*)((char*)d_ws + 256);
  double* flsl = (double*)((char*)d_ws + 256 + (size_t)N_IMFS * N_ITER * 2 * 8);
  hipLaunchKernelGGL(emd_main, dim3(NB), dim3(NT), 0, stream, x, out, cnt, sdsl, flsl);
}